// Round 3
// baseline (202.418 us; speedup 1.0000x reference)
//
#include <hip/hip_runtime.h>

#define BB 4
#define CCH 64
#define LLEN 4096
#define QSCALE 0.125f
#define TQ 64
#define TK 64
#define NCHUNK 8
#define TPC 8          // lk tiles per chunk (8*64 = 512)
#define NTB 256

typedef __bf16 bf16;
typedef bf16 bf16x4 __attribute__((ext_vector_type(4)));
typedef bf16 bf16x8 __attribute__((ext_vector_type(8)));
typedef float f32x4 __attribute__((ext_vector_type(4)));

// swizzled element index into a [64 rows][64 cols] bf16 tile (128B rows)
__device__ __forceinline__ int swz(int row, int col) {
    return row * 64 + (col ^ ((row & 7) << 3));
}

// ---------------- Kernel A: per-chunk row stats (m, s) + zero out ----------------
__global__ __launch_bounds__(NTB) void attn_stats(
    const float* __restrict__ qg, const float* __restrict__ kg,
    const float* __restrict__ maskg, float* __restrict__ ws,
    float* __restrict__ outp)
{
    __shared__ __align__(16) bf16 qs[TQ * CCH];
    __shared__ __align__(16) bf16 ks[TK * CCH];
    __shared__ float lms[TK];

    const int tid = threadIdx.x;
    const int l = tid & 63;
    const int w = tid >> 6;
    const int strip = w * 16;
    const int g = l >> 4;
    const int cl = l & 15;

    const int idx = blockIdx.x;
    const int chunk = idx & (NCHUNK - 1);
    const int lqt = (idx >> 3) & 63;
    const int b = idx >> 9;
    const int lq0 = lqt * TQ;
    const size_t qkvbase = (size_t)b * CCH * LLEN;

    // zero the out region (exactly 2 floats per thread across the grid)
    {
        size_t oidx = ((size_t)blockIdx.x * NTB + tid) * 2;
        *(float2*)&outp[oidx] = make_float2(0.f, 0.f);
    }

    // stage Q^T: qs[lq][c] swz
    {
        int q2 = (tid & 31) * 2;
        int c0 = tid >> 5;  // 0..7
#pragma unroll
        for (int cp = 0; cp < 8; ++cp) {
            int c = c0 + cp * 8;
            const float2 f = *(const float2*)&qg[qkvbase + (size_t)c * LLEN + lq0 + q2];
            qs[swz(q2, c)] = (bf16)f.x;
            qs[swz(q2 + 1, c)] = (bf16)f.y;
        }
    }
    __syncthreads();

    bf16x8 qf[2];
    qf[0] = *(const bf16x8*)&qs[swz(strip + cl, 8 * g)];
    qf[1] = *(const bf16x8*)&qs[swz(strip + cl, 32 + 8 * g)];

    float m_run = -3.0e38f, s_run = 0.0f;

    for (int it = 0; it < TPC; ++it) {
        const int lk0 = chunk * (TPC * TK) + it * TK;
        __syncthreads();
        {
            int q2 = (tid & 31) * 2;
            int c0 = tid >> 5;
#pragma unroll
            for (int cp = 0; cp < 8; ++cp) {
                int c = c0 + cp * 8;
                const float2 f = *(const float2*)&kg[qkvbase + (size_t)c * LLEN + lk0 + q2];
                ks[swz(q2, c)] = (bf16)f.x;
                ks[swz(q2 + 1, c)] = (bf16)f.y;
            }
            if (tid < TK)
                lms[tid] = __logf(maskg[(size_t)b * LLEN + lk0 + tid] + 1e-6f);
        }
        __syncthreads();

        f32x4 e4[4];
#pragma unroll
        for (int t = 0; t < 4; ++t) e4[t] = (f32x4){0.f, 0.f, 0.f, 0.f};
#pragma unroll
        for (int s = 0; s < 2; ++s)
#pragma unroll
            for (int t = 0; t < 4; ++t) {
                bf16x8 kf = *(const bf16x8*)&ks[swz(16 * t + cl, 32 * s + 8 * g)];
                e4[t] = __builtin_amdgcn_mfma_f32_16x16x32_bf16(kf, qf[s], e4[t], 0, 0, 0);
            }

        float ev[4][4];
        float tmax = -3.0e38f;
#pragma unroll
        for (int t = 0; t < 4; ++t)
#pragma unroll
            for (int r = 0; r < 4; ++r) {
                ev[t][r] = e4[t][r] * QSCALE + lms[16 * t + 4 * g + r];
                tmax = fmaxf(tmax, ev[t][r]);
            }
        tmax = fmaxf(tmax, __shfl_xor(tmax, 16));
        tmax = fmaxf(tmax, __shfl_xor(tmax, 32));
        float m_new = fmaxf(m_run, tmax);
        float ps = 0.f;
#pragma unroll
        for (int t = 0; t < 4; ++t)
#pragma unroll
            for (int r = 0; r < 4; ++r) ps += __expf(ev[t][r] - m_new);
        ps += __shfl_xor(ps, 16);
        ps += __shfl_xor(ps, 32);
        s_run = s_run * __expf(m_run - m_new) + ps;
        m_run = m_new;
    }

    if (l < 16) {  // g == 0 lanes hold valid reduced stats
        size_t row = (size_t)b * LLEN + lq0 + strip + cl;
        ws[(row * NCHUNK + chunk) * 2 + 0] = m_run;
        ws[(row * NCHUNK + chunk) * 2 + 1] = s_run;
    }
}

// ---------------- Kernel B: normalize, write attnT, PV (atomic merge) ----------------
__global__ __launch_bounds__(NTB) void attn_emit(
    const float* __restrict__ qg, const float* __restrict__ kg,
    const float* __restrict__ vg, const float* __restrict__ maskg,
    const float* __restrict__ ws, float* __restrict__ outp,
    float* __restrict__ attnT)
{
    __shared__ __align__(16) bf16 qs[TQ * CCH];
    __shared__ __align__(16) bf16 ks[TK * CCH];
    __shared__ __align__(16) bf16 vs[CCH * TK];
    __shared__ float lms[TK];
    __shared__ float mvs[TK];

    const int tid = threadIdx.x;
    const int l = tid & 63;
    const int w = tid >> 6;
    const int strip = w * 16;
    const int g = l >> 4;
    const int cl = l & 15;

    const int idx = blockIdx.x;
    const int chunk = idx & (NCHUNK - 1);
    const int lqt = (idx >> 3) & 63;
    const int b = idx >> 9;
    const int lq0 = lqt * TQ;
    const size_t qkvbase = (size_t)b * CCH * LLEN;

    // stage Q^T
    {
        int q2 = (tid & 31) * 2;
        int c0 = tid >> 5;
#pragma unroll
        for (int cp = 0; cp < 8; ++cp) {
            int c = c0 + cp * 8;
            const float2 f = *(const float2*)&qg[qkvbase + (size_t)c * LLEN + lq0 + q2];
            qs[swz(q2, c)] = (bf16)f.x;
            qs[swz(q2 + 1, c)] = (bf16)f.y;
        }
    }

    // merge global row stats for this lane's lq
    float m_f, inv_s;
    {
        size_t row = (size_t)b * LLEN + lq0 + strip + cl;
        const float2* wp = (const float2*)&ws[row * NCHUNK * 2];
        float2 st[NCHUNK];
#pragma unroll
        for (int i = 0; i < NCHUNK; ++i) st[i] = wp[i];
        m_f = -3.0e38f;
#pragma unroll
        for (int i = 0; i < NCHUNK; ++i) m_f = fmaxf(m_f, st[i].x);
        float sf = 0.f;
#pragma unroll
        for (int i = 0; i < NCHUNK; ++i) sf += st[i].y * __expf(st[i].x - m_f);
        inv_s = 1.0f / sf;
    }
    __syncthreads();

    bf16x8 qf[2];
    qf[0] = *(const bf16x8*)&qs[swz(strip + cl, 8 * g)];
    qf[1] = *(const bf16x8*)&qs[swz(strip + cl, 32 + 8 * g)];

    f32x4 o4[4];
#pragma unroll
    for (int t = 0; t < 4; ++t) o4[t] = (f32x4){0.f, 0.f, 0.f, 0.f};

    for (int it = 0; it < TPC; ++it) {
        const int lk0 = chunk * (TPC * TK) + it * TK;
        __syncthreads();
        {
            int q2 = (tid & 31) * 2;
            int c0 = tid >> 5;
#pragma unroll
            for (int cp = 0; cp < 8; ++cp) {
                int c = c0 + cp * 8;
                const float2 f = *(const float2*)&kg[qkvbase + (size_t)c * LLEN + lk0 + q2];
                ks[swz(q2, c)] = (bf16)f.x;
                ks[swz(q2 + 1, c)] = (bf16)f.y;
            }
            int lk4 = (tid & 15) * 4;
            int cv0 = tid >> 4;  // 0..15
#pragma unroll
            for (int cp = 0; cp < 4; ++cp) {
                int c = cv0 + cp * 16;
                const float4 f = *(const float4*)&vg[qkvbase + (size_t)c * LLEN + lk0 + lk4];
                bf16x4 v4 = {(bf16)f.x, (bf16)f.y, (bf16)f.z, (bf16)f.w};
                *(bf16x4*)&vs[swz(c, lk4)] = v4;
            }
            if (tid < TK) {
                float mv = maskg[(size_t)b * LLEN + lk0 + tid];
                lms[tid] = __logf(mv + 1e-6f);
                mvs[tid] = mv;
            }
        }
        __syncthreads();

        f32x4 e4[4];
#pragma unroll
        for (int t = 0; t < 4; ++t) e4[t] = (f32x4){0.f, 0.f, 0.f, 0.f};
#pragma unroll
        for (int s = 0; s < 2; ++s)
#pragma unroll
            for (int t = 0; t < 4; ++t) {
                bf16x8 kf = *(const bf16x8*)&ks[swz(16 * t + cl, 32 * s + 8 * g)];
                e4[t] = __builtin_amdgcn_mfma_f32_16x16x32_bf16(kf, qf[s], e4[t], 0, 0, 0);
            }

        float p[4][4];
#pragma unroll
        for (int t = 0; t < 4; ++t)
#pragma unroll
            for (int r = 0; r < 4; ++r) {
                int lk = 16 * t + 4 * g + r;
                float evv = e4[t][r] * QSCALE + lms[lk];
                p[t][r] = __expf(evv - m_f) * inv_s * mvs[lk];
            }

        // attnT write: per (t,r) lanes cover 4 rows x 64B contiguous
#pragma unroll
        for (int t = 0; t < 4; ++t)
#pragma unroll
            for (int r = 0; r < 4; ++r) {
                int lkg = lk0 + 16 * t + 4 * g + r;
                attnT[((size_t)b * LLEN + lkg) * LLEN + lq0 + strip + cl] = p[t][r];
            }

        // PV: A = V, B = P (lane-local)
        bf16x8 pb[2];
#pragma unroll
        for (int s = 0; s < 2; ++s)
#pragma unroll
            for (int j = 0; j < 8; ++j)
                pb[s][j] = (bf16)p[2 * s + (j >> 2)][j & 3];
#pragma unroll
        for (int s = 0; s < 2; ++s)
#pragma unroll
            for (int mt = 0; mt < 4; ++mt) {
                int c = 16 * mt + cl;
                bf16x4 vlo = *(const bf16x4*)&vs[swz(c, 32 * s + 4 * g)];
                bf16x4 vhi = *(const bf16x4*)&vs[swz(c, 32 * s + 16 + 4 * g)];
                bf16x8 vf = __builtin_shufflevector(vlo, vhi, 0, 1, 2, 3, 4, 5, 6, 7);
                o4[mt] = __builtin_amdgcn_mfma_f32_16x16x32_bf16(vf, pb[s], o4[mt], 0, 0, 0);
            }
    }

    // merge partial PV into out (8 chunk-blocks per element)
#pragma unroll
    for (int mt = 0; mt < 4; ++mt)
#pragma unroll
        for (int r = 0; r < 4; ++r) {
            int c = 16 * mt + 4 * g + r;
            atomicAdd(&outp[qkvbase + (size_t)c * LLEN + lq0 + strip + cl], o4[mt][r]);
        }
}

extern "C" void kernel_launch(void* const* d_in, const int* in_sizes, int n_in,
                              void* d_out, int out_size, void* d_ws, size_t ws_size,
                              hipStream_t stream) {
    const float* qg = (const float*)d_in[0];
    const float* kg = (const float*)d_in[1];
    const float* vg = (const float*)d_in[2];
    const float* mg = (const float*)d_in[3];
    float* outp = (float*)d_out;
    float* attnT = outp + (size_t)BB * CCH * LLEN;
    float* ws = (float*)d_ws;  // [B*L][NCHUNK][2] floats = 1 MB

    dim3 grid(BB * (LLEN / TQ) * NCHUNK);
    dim3 block(NTB);
    attn_stats<<<grid, block, 0, stream>>>(qg, kg, mg, ws, outp);
    attn_emit<<<grid, block, 0, stream>>>(qg, kg, vg, mg, ws, outp, attnT);
}

// Round 4
// 120.868 us; speedup vs baseline: 1.6747x; 1.6747x over previous
//
#include <hip/hip_runtime.h>
#include <stdint.h>

#define BB 4
#define CCH 64
#define LLEN 4096
#define QSCALE 0.125f
#define TQ 64
#define TK 64
#define NCHUNK 8
#define TPC 8
#define NTB 256

typedef __bf16 bf16;
typedef bf16 bf16x4 __attribute__((ext_vector_type(4)));
typedef bf16 bf16x8 __attribute__((ext_vector_type(8)));
typedef float f32x4 __attribute__((ext_vector_type(4)));

// swizzled element index into a [64 rows][64 cols] bf16 tile (128B rows)
__device__ __forceinline__ int swz(int row, int col) {
    return row * 64 + (col ^ ((row & 7) << 3));
}

__device__ __forceinline__ void g2l16(const void* g, void* l) {
    __builtin_amdgcn_global_load_lds(
        (const __attribute__((address_space(1))) void*)g,
        (__attribute__((address_space(3))) void*)l, 16, 0, 0);
}

#define WAITVM(n) asm volatile("s_waitcnt vmcnt(" #n ")" ::: "memory")
#define WAITLGKM0 asm volatile("s_waitcnt lgkmcnt(0)" ::: "memory")
#define BAR() __builtin_amdgcn_s_barrier()

// copy one 8KB contiguous 64x64 bf16 tile global->LDS (8 instrs, 2 per wave)
__device__ __forceinline__ void stage_rows(const bf16* src, bf16* dst, int w, int l) {
#pragma unroll
    for (int i = 0; i < 2; ++i) {
        int ci = w * 2 + i;
        g2l16(src + ci * 512 + l * 8, dst + ci * 512);
    }
}
// stage V tile: rows c=0..63 of 64 elems at stride LLEN -> linear LDS [c][64]
__device__ __forceinline__ void stage_v(const bf16* vb, int lk0, bf16* dst, int w, int l) {
#pragma unroll
    for (int i = 0; i < 2; ++i) {
        int ci = w * 2 + i;
        int G = ci * 64 + l;
        int c = G >> 3, gg = G & 7;
        g2l16(vb + (size_t)c * LLEN + lk0 + gg * 8, dst + ci * 512);
    }
}

// ---------------- prep: Q,K -> bf16 transposed [lk][c] pre-swizzled ----------------
__global__ __launch_bounds__(NTB) void prep_qk(
    const float* __restrict__ qg, const float* __restrict__ kg,
    bf16* __restrict__ qT, bf16* __restrict__ kT)
{
    __shared__ float t[64][65];
    const int tid = threadIdx.x;
    const int isK = blockIdx.x >> 8;
    const int idx = blockIdx.x & 255;
    const int b = idx >> 6;
    const int lt = idx & 63;
    const float* src = (isK ? kg : qg) + (size_t)b * CCH * LLEN + lt * 64;
    bf16* dst = (isK ? kT : qT) + ((size_t)b * LLEN + lt * 64) * 64;

    int c = tid >> 2, x0 = (tid & 3) * 16;
#pragma unroll
    for (int j = 0; j < 4; ++j) {
        float4 f = *(const float4*)&src[(size_t)c * LLEN + x0 + j * 4];
        t[c][x0 + j * 4 + 0] = f.x;
        t[c][x0 + j * 4 + 1] = f.y;
        t[c][x0 + j * 4 + 2] = f.z;
        t[c][x0 + j * 4 + 3] = f.w;
    }
    __syncthreads();
    int lk = tid >> 2;
    int g0 = (tid & 3) * 2;
#pragma unroll
    for (int gi = 0; gi < 2; ++gi) {
        int gg = g0 + gi;
        bf16x8 v;
#pragma unroll
        for (int j = 0; j < 8; ++j) v[j] = (bf16)t[gg * 8 + j][lk];
        *(bf16x8*)&dst[lk * 64 + ((gg ^ (lk & 7)) * 8)] = v;
    }
}

// ---------------- prep: V -> bf16 [c][lk] per-64-tile pre-swizzled; mask factors ----------------
__global__ __launch_bounds__(NTB) void prep_vm(
    const float* __restrict__ vg, const float* __restrict__ mg,
    bf16* __restrict__ vN, float* __restrict__ wS, float* __restrict__ wE)
{
    const int tid = threadIdx.x;
    if (blockIdx.x < 256) {
        const int row = blockIdx.x;  // b*64 + c
        const int c = row & 63;
        const size_t base = (size_t)row * LLEN;
        int x0 = tid * 16;
        float f[16];
#pragma unroll
        for (int j = 0; j < 4; ++j) {
            float4 v4 = *(const float4*)&vg[base + x0 + j * 4];
            f[j * 4 + 0] = v4.x; f[j * 4 + 1] = v4.y;
            f[j * 4 + 2] = v4.z; f[j * 4 + 3] = v4.w;
        }
#pragma unroll
        for (int h = 0; h < 2; ++h) {
            int gl = ((x0 >> 3) + h) & 7;
            int tb = (x0 + h * 8) & ~63;
            bf16x8 v;
#pragma unroll
            for (int j = 0; j < 8; ++j) v[j] = (bf16)f[h * 8 + j];
            *(bf16x8*)&vN[base + tb + ((gl ^ (c & 7)) * 8)] = v;
        }
    } else {
        const int b = blockIdx.x - 256;
        int x0 = tid * 16;
#pragma unroll
        for (int j = 0; j < 16; ++j) {
            float m = mg[(size_t)b * LLEN + x0 + j];
            float w = m + 1e-6f;
            wS[(size_t)b * LLEN + x0 + j] = w;
            wE[(size_t)b * LLEN + x0 + j] = w * m;
        }
    }
}

// ---------------- stats: per-chunk row sums of exp(e)*w; zero out ----------------
__global__ __launch_bounds__(NTB) void attn_stats(
    const bf16* __restrict__ qT, const bf16* __restrict__ kT,
    const float* __restrict__ wS, float* __restrict__ sums,
    float* __restrict__ outp)
{
    __shared__ __align__(16) bf16 kbuf[2][TK * CCH];
    __shared__ __align__(16) float wbuf[2][TK];

    const int tid = threadIdx.x;
    const int l = tid & 63;
    const int w = tid >> 6;
    const int strip = w * 16;
    const int g = l >> 4;
    const int cl = l & 15;

    const int idx = blockIdx.x;
    const int chunk = idx & 7;
    const int lqt = (idx >> 3) & 63;
    const int b = idx >> 9;
    const int lq0 = lqt * TQ;

    // zero out region (exactly 2 floats per thread across the grid)
    {
        size_t o = ((size_t)idx * NTB + tid) * 2;
        *(float2*)&outp[o] = make_float2(0.f, 0.f);
    }

    // stage Q into kbuf[0]
    stage_rows(qT + ((size_t)b * LLEN + lq0) * 64, kbuf[0], w, l);
    WAITVM(0);
    BAR();
    bf16x8 qf0 = *(const bf16x8*)&kbuf[0][swz(strip + cl, 8 * g)];
    bf16x8 qf1 = *(const bf16x8*)&kbuf[0][swz(strip + cl, 32 + 8 * g)];
    WAITLGKM0;
    BAR();

    // prologue: tile 0 into buf0
    {
        const int lk0 = chunk * (TPC * TK);
        if (w == 0 && l < 16) g2l16(wS + (size_t)b * LLEN + lk0 + l * 4, wbuf[0]);
        stage_rows(kT + ((size_t)b * LLEN + lk0) * 64, kbuf[0], w, l);
    }

    float sacc = 0.f;
#pragma unroll
    for (int it = 0; it < TPC; ++it) {
        const int cur = it & 1;
        if (it < TPC - 1) {
            const int lk1 = chunk * (TPC * TK) + (it + 1) * TK;
            if (w == 0 && l < 16) g2l16(wS + (size_t)b * LLEN + lk1 + l * 4, wbuf[cur ^ 1]);
            stage_rows(kT + ((size_t)b * LLEN + lk1) * 64, kbuf[cur ^ 1], w, l);
        }
        if (it == TPC - 1) { WAITVM(0); }
        else { if (w == 0) { WAITVM(3); } else { WAITVM(2); } }
        BAR();

        f32x4 e4[4];
#pragma unroll
        for (int t = 0; t < 4; ++t) e4[t] = (f32x4){0.f, 0.f, 0.f, 0.f};
#pragma unroll
        for (int t = 0; t < 4; ++t) {
            bf16x8 kf0 = *(const bf16x8*)&kbuf[cur][swz(16 * t + cl, 8 * g)];
            e4[t] = __builtin_amdgcn_mfma_f32_16x16x32_bf16(kf0, qf0, e4[t], 0, 0, 0);
            bf16x8 kf1 = *(const bf16x8*)&kbuf[cur][swz(16 * t + cl, 32 + 8 * g)];
            e4[t] = __builtin_amdgcn_mfma_f32_16x16x32_bf16(kf1, qf1, e4[t], 0, 0, 0);
        }
#pragma unroll
        for (int t = 0; t < 4; ++t)
#pragma unroll
            for (int r = 0; r < 4; ++r)
                sacc += __expf(e4[t][r] * QSCALE) * wbuf[cur][16 * t + 4 * g + r];

        WAITLGKM0;
        BAR();
    }

    sacc += __shfl_xor(sacc, 16);
    sacc += __shfl_xor(sacc, 32);
    if (l < 16)
        sums[((size_t)b * LLEN + lq0 + strip + cl) * NCHUNK + chunk] = sacc;
}

// ---------------- emit: recompute QK, normalize, write attnT, PV + atomic out ----------------
__global__ __launch_bounds__(NTB) void attn_emit(
    const bf16* __restrict__ qT, const bf16* __restrict__ kT,
    const bf16* __restrict__ vN, const float* __restrict__ wE,
    const float* __restrict__ sums, float* __restrict__ outp,
    float* __restrict__ attnT)
{
    __shared__ __align__(16) bf16 kbuf[2][TK * CCH];
    __shared__ __align__(16) bf16 vbuf[2][TK * CCH];
    __shared__ __align__(16) float wbuf[2][TK];

    const int tid = threadIdx.x;
    const int l = tid & 63;
    const int w = tid >> 6;
    const int strip = w * 16;
    const int g = l >> 4;
    const int cl = l & 15;

    const int idx = blockIdx.x;
    const int chunk = idx & 7;
    const int lqt = (idx >> 3) & 63;
    const int b = idx >> 9;
    const int lq0 = lqt * TQ;
    const size_t obase = (size_t)b * CCH * LLEN;
    const bf16* vb = vN + obase;

    // stage Q into kbuf[0]; read row sums
    stage_rows(qT + ((size_t)b * LLEN + lq0) * 64, kbuf[0], w, l);
    float ssum;
    {
        const float4* sp = (const float4*)&sums[((size_t)b * LLEN + lq0 + strip + cl) * NCHUNK];
        float4 a = sp[0], c4 = sp[1];
        ssum = ((a.x + a.y) + (a.z + a.w)) + ((c4.x + c4.y) + (c4.z + c4.w));
    }
    const float inv_s = 1.0f / ssum;
    WAITVM(0);
    BAR();
    bf16x8 qf0 = *(const bf16x8*)&kbuf[0][swz(strip + cl, 8 * g)];
    bf16x8 qf1 = *(const bf16x8*)&kbuf[0][swz(strip + cl, 32 + 8 * g)];
    WAITLGKM0;
    BAR();

    // prologue: tile 0
    {
        const int lk0 = chunk * (TPC * TK);
        if (w == 0 && l < 16) g2l16(wE + (size_t)b * LLEN + lk0 + l * 4, wbuf[0]);
        stage_rows(kT + ((size_t)b * LLEN + lk0) * 64, kbuf[0], w, l);
        stage_v(vb, lk0, vbuf[0], w, l);
    }

    f32x4 o4[4];
#pragma unroll
    for (int t = 0; t < 4; ++t) o4[t] = (f32x4){0.f, 0.f, 0.f, 0.f};

#pragma unroll
    for (int it = 0; it < TPC; ++it) {
        const int cur = it & 1;
        const int lk0 = chunk * (TPC * TK) + it * TK;
        if (it < TPC - 1) {
            const int lk1 = lk0 + TK;
            if (w == 0 && l < 16) g2l16(wE + (size_t)b * LLEN + lk1 + l * 4, wbuf[cur ^ 1]);
            stage_rows(kT + ((size_t)b * LLEN + lk1) * 64, kbuf[cur ^ 1], w, l);
            stage_v(vb, lk1, vbuf[cur ^ 1], w, l);
        }
        // wait for tile-it loads: newer ops = [stores of it-1 (16)] + [loads of it+1 (4|5)]
        if (it == 0)            { if (w == 0) { WAITVM(5);  } else { WAITVM(4);  } }
        else if (it < TPC - 1)  { if (w == 0) { WAITVM(21); } else { WAITVM(20); } }
        else                    { WAITVM(16); }
        BAR();

        f32x4 e4[4];
#pragma unroll
        for (int t = 0; t < 4; ++t) e4[t] = (f32x4){0.f, 0.f, 0.f, 0.f};
#pragma unroll
        for (int t = 0; t < 4; ++t) {
            bf16x8 kf0 = *(const bf16x8*)&kbuf[cur][swz(16 * t + cl, 8 * g)];
            e4[t] = __builtin_amdgcn_mfma_f32_16x16x32_bf16(kf0, qf0, e4[t], 0, 0, 0);
            bf16x8 kf1 = *(const bf16x8*)&kbuf[cur][swz(16 * t + cl, 32 + 8 * g)];
            e4[t] = __builtin_amdgcn_mfma_f32_16x16x32_bf16(kf1, qf1, e4[t], 0, 0, 0);
        }

        float p[4][4];
#pragma unroll
        for (int t = 0; t < 4; ++t)
#pragma unroll
            for (int r = 0; r < 4; ++r)
                p[t][r] = __expf(e4[t][r] * QSCALE) * wbuf[cur][16 * t + 4 * g + r] * inv_s;

        // attnT stores: per (t,r) lanes cover 4 rows x 64B contiguous
#pragma unroll
        for (int t = 0; t < 4; ++t)
#pragma unroll
            for (int r = 0; r < 4; ++r) {
                int lkg = lk0 + 16 * t + 4 * g + r;
                attnT[((size_t)b * LLEN + lkg) * LLEN + lq0 + strip + cl] = p[t][r];
            }

        // PV: A = V, B = P (lane-local)
        bf16x8 pb[2];
#pragma unroll
        for (int s = 0; s < 2; ++s)
#pragma unroll
            for (int j = 0; j < 8; ++j)
                pb[s][j] = (bf16)p[2 * s + (j >> 2)][j & 3];
#pragma unroll
        for (int s = 0; s < 2; ++s)
#pragma unroll
            for (int mt = 0; mt < 4; ++mt) {
                int c = 16 * mt + cl;
                bf16x4 vlo = *(const bf16x4*)&vbuf[cur][swz(c, 32 * s + 4 * g)];
                bf16x4 vhi = *(const bf16x4*)&vbuf[cur][swz(c, 32 * s + 16 + 4 * g)];
                bf16x8 vf = __builtin_shufflevector(vlo, vhi, 0, 1, 2, 3, 4, 5, 6, 7);
                o4[mt] = __builtin_amdgcn_mfma_f32_16x16x32_bf16(vf, pb[s], o4[mt], 0, 0, 0);
            }

        WAITLGKM0;
        BAR();
    }

    // merge partial PV into out
#pragma unroll
    for (int mt = 0; mt < 4; ++mt)
#pragma unroll
        for (int r = 0; r < 4; ++r) {
            int c = 16 * mt + 4 * g + r;
            atomicAdd(&outp[obase + (size_t)c * LLEN + lq0 + strip + cl], o4[mt][r]);
        }
}

extern "C" void kernel_launch(void* const* d_in, const int* in_sizes, int n_in,
                              void* d_out, int out_size, void* d_ws, size_t ws_size,
                              hipStream_t stream) {
    const float* qg = (const float*)d_in[0];
    const float* kg = (const float*)d_in[1];
    const float* vg = (const float*)d_in[2];
    const float* mg = (const float*)d_in[3];
    float* outp = (float*)d_out;
    float* attnT = outp + (size_t)BB * CCH * LLEN;

    char* ws = (char*)d_ws;
    bf16* qT = (bf16*)ws;                                  // 2 MB
    bf16* kT = (bf16*)(ws + (2u << 20));                   // 2 MB
    bf16* vN = (bf16*)(ws + (4u << 20));                   // 2 MB
    float* wS = (float*)(ws + (6u << 20));                 // 64 KB
    float* wE = (float*)(ws + (6u << 20) + (64u << 10));   // 64 KB
    float* sums = (float*)(ws + (6u << 20) + (128u << 10)); // 512 KB

    prep_qk<<<512, NTB, 0, stream>>>(qg, kg, qT, kT);
    prep_vm<<<260, NTB, 0, stream>>>(vg, mg, vN, wS, wE);
    attn_stats<<<BB * (LLEN / TQ) * NCHUNK, NTB, 0, stream>>>(qT, kT, wS, sums, outp);
    attn_emit<<<BB * (LLEN / TQ) * NCHUNK, NTB, 0, stream>>>(qT, kT, vN, wE, sums, outp, attnT);
}